// Round 2
// baseline (110.181 us; speedup 1.0000x reference)
//
#include <hip/hip_runtime.h>

// JaccardLoss: per-(B,C) slice IoU of the ==1 masks, mean over slices, x100.
// B=32, C=1, H=W=1024, fp32 inputs holding exactly 0.0/1.0.
// Memory-bound: 268 MB read. Single fused kernel with last-block finalize.

#define SLICES 32
#define SLICE_F4 (1024 * 1024 / 4)          // 262144 float4 per slice
#define BPS 64                               // blocks per slice
#define GRID (SLICES * BPS)                  // 2048 blocks
#define CHUNK_F4 (SLICE_F4 / BPS)            // 4096 float4 per block
#define THREADS 256
#define ITERS (CHUNK_F4 / THREADS)           // 16 float4 pairs per thread

typedef unsigned long long u64;

__device__ __forceinline__ void acc4(const float4 A, const float4 B, int& I, int& U) {
    bool a0 = (A.x == 1.0f), a1 = (A.y == 1.0f), a2 = (A.z == 1.0f), a3 = (A.w == 1.0f);
    bool b0 = (B.x == 1.0f), b1 = (B.y == 1.0f), b2 = (B.z == 1.0f), b3 = (B.w == 1.0f);
    I += (int)(a0 && b0) + (int)(a1 && b1) + (int)(a2 && b2) + (int)(a3 && b3);
    U += (int)(a0 || b0) + (int)(a1 || b1) + (int)(a2 || b2) + (int)(a3 || b3);
}

__global__ __launch_bounds__(THREADS) void jaccard_fused(
    const float4* __restrict__ a, const float4* __restrict__ b,
    u64* __restrict__ partial /* [GRID] = (U<<32)|I */,
    unsigned* __restrict__ done, float* __restrict__ out) {
    const int slice = blockIdx.x >> 6;            // BPS == 64
    const int sub   = blockIdx.x & (BPS - 1);
    const size_t base = (size_t)slice * SLICE_F4 + (size_t)sub * CHUNK_F4 + threadIdx.x;

    int I = 0, U = 0;
    #pragma unroll 4
    for (int i = 0; i < ITERS; ++i) {
        float4 A = a[base + (size_t)i * THREADS];
        float4 B = b[base + (size_t)i * THREADS];
        acc4(A, B, I, U);
    }

    // wave-64 reduce
    for (int off = 32; off; off >>= 1) {
        I += __shfl_down(I, off);
        U += __shfl_down(U, off);
    }

    __shared__ int sI[THREADS / 64], sU[THREADS / 64];
    __shared__ int lastFlag;
    __shared__ float sIou[SLICES];
    const int wid = threadIdx.x >> 6, lane = threadIdx.x & 63;
    if (lane == 0) { sI[wid] = I; sU[wid] = U; }
    __syncthreads();
    if (threadIdx.x == 0) {
        int bI = 0, bU = 0;
        #pragma unroll
        for (int w = 0; w < THREADS / 64; ++w) { bI += sI[w]; bU += sU[w]; }
        u64 v = ((u64)(unsigned)bU << 32) | (u64)(unsigned)bI;
        // agent-scope atomic store: bypasses incoherent L1/L2 so the final
        // block (possibly another XCD) sees it.
        __hip_atomic_store(&partial[blockIdx.x], v, __ATOMIC_RELAXED, __HIP_MEMORY_SCOPE_AGENT);
        unsigned old = __hip_atomic_fetch_add(done, 1u, __ATOMIC_ACQ_REL, __HIP_MEMORY_SCOPE_AGENT);
        lastFlag = (old == GRID - 1);
    }
    __syncthreads();
    if (!lastFlag) return;

    // ---- last block: reduce 2048 partials, write result ----
    const int t = threadIdx.x;
    const int s = t >> 3;               // slice 0..31, 8 threads each
    const int j0 = (t & 7) * 8;         // 8 partials per thread
    int fI = 0, fU = 0;
    #pragma unroll
    for (int j = 0; j < 8; ++j) {
        u64 v = __hip_atomic_load(&partial[s * BPS + j0 + j], __ATOMIC_RELAXED,
                                  __HIP_MEMORY_SCOPE_AGENT);
        fI += (int)(unsigned)(v & 0xffffffffu);
        fU += (int)(unsigned)(v >> 32);
    }
    #pragma unroll
    for (int m = 1; m < 8; m <<= 1) {   // 8-lane group reduce (within wave)
        fI += __shfl_xor(fI, m);
        fU += __shfl_xor(fU, m);
    }
    if ((t & 7) == 0) sIou[s] = (float)fI / ((float)fU + 1e-7f);
    __syncthreads();
    if (t < 64) {
        float x = (t < SLICES) ? sIou[t] : 0.0f;
        for (int off = 32; off; off >>= 1) x += __shfl_down(x, off);
        if (t == 0) out[0] = x * (100.0f / (float)SLICES);
    }
}

extern "C" void kernel_launch(void* const* d_in, const int* in_sizes, int n_in,
                              void* d_out, int out_size, void* d_ws, size_t ws_size,
                              hipStream_t stream) {
    const float4* A = (const float4*)d_in[0];
    const float4* B = (const float4*)d_in[1];
    u64* partial = (u64*)d_ws;
    unsigned* done = (unsigned*)((char*)d_ws + GRID * sizeof(u64));
    float* out = (float*)d_out;

    // zero just the completion counter (4 B) each call; partials need no init
    hipMemsetAsync(done, 0, sizeof(unsigned), stream);
    jaccard_fused<<<GRID, THREADS, 0, stream>>>(A, B, partial, done, out);
}

// Round 3
// 44.310 us; speedup vs baseline: 2.4866x; 2.4866x over previous
//
#include <hip/hip_runtime.h>

// JaccardLoss: per-(B,C) slice IoU of the ==1 masks, mean over slices, x100.
// B=32, C=1, H=W=1024, fp32 inputs holding exactly 0.0/1.0.
// Memory-bound streaming reduction: 268 MB read.
//
// Structure: count kernel (2048 blocks, plain-store per-block partials into
// d_ws -- every slot written every call, so no init/memset needed) + tiny
// finalize kernel. NO atomics: round-2 showed agent-scope acq-rel atomics
// cost ~100ns of L2 maintenance per block (196us total, even cache-resident).

#define SLICES 32
#define SLICE_F4 (1024 * 1024 / 4)           // 262144 float4 per slice
#define BPS 64                                // blocks per slice
#define GRID (SLICES * BPS)                   // 2048 blocks
#define CHUNK_F4 (SLICE_F4 / BPS)             // 4096 float4 per block
#define THREADS 256
#define ITERS (CHUNK_F4 / THREADS)            // 16 float4 pairs per thread

typedef unsigned long long u64;

__device__ __forceinline__ void acc4(const float4 A, const float4 B, int& I, int& U) {
    bool a0 = (A.x == 1.0f), a1 = (A.y == 1.0f), a2 = (A.z == 1.0f), a3 = (A.w == 1.0f);
    bool b0 = (B.x == 1.0f), b1 = (B.y == 1.0f), b2 = (B.z == 1.0f), b3 = (B.w == 1.0f);
    I += (int)(a0 && b0) + (int)(a1 && b1) + (int)(a2 && b2) + (int)(a3 && b3);
    U += (int)(a0 || b0) + (int)(a1 || b1) + (int)(a2 || b2) + (int)(a3 || b3);
}

__global__ __launch_bounds__(THREADS) void jaccard_count(
    const float4* __restrict__ a, const float4* __restrict__ b,
    u64* __restrict__ partial /* [GRID] = (U<<32)|I */) {
    const int slice = blockIdx.x >> 6;         // BPS == 64
    const int sub   = blockIdx.x & (BPS - 1);
    const size_t base = (size_t)slice * SLICE_F4 + (size_t)sub * CHUNK_F4 + threadIdx.x;

    int I = 0, U = 0;
    #pragma unroll 2
    for (int i = 0; i < ITERS; i += 2) {       // 2-way interleave: 4 loads in flight
        float4 A0 = a[base + (size_t)(i + 0) * THREADS];
        float4 B0 = b[base + (size_t)(i + 0) * THREADS];
        float4 A1 = a[base + (size_t)(i + 1) * THREADS];
        float4 B1 = b[base + (size_t)(i + 1) * THREADS];
        acc4(A0, B0, I, U);
        acc4(A1, B1, I, U);
    }

    // wave-64 reduce
    for (int off = 32; off; off >>= 1) {
        I += __shfl_down(I, off);
        U += __shfl_down(U, off);
    }

    __shared__ int sI[THREADS / 64], sU[THREADS / 64];
    const int wid = threadIdx.x >> 6, lane = threadIdx.x & 63;
    if (lane == 0) { sI[wid] = I; sU[wid] = U; }
    __syncthreads();
    if (threadIdx.x == 0) {
        int bI = 0, bU = 0;
        #pragma unroll
        for (int w = 0; w < THREADS / 64; ++w) { bI += sI[w]; bU += sU[w]; }
        partial[blockIdx.x] = ((u64)(unsigned)bU << 32) | (u64)(unsigned)bI;
    }
}

__global__ __launch_bounds__(THREADS) void jaccard_final(
    const u64* __restrict__ partial, float* __restrict__ out) {
    const int t = threadIdx.x;                 // 256 threads
    const int s = t >> 3;                      // slice 0..31, 8 threads each
    const int j0 = (t & 7) * 8;                // 8 partials per thread
    int fI = 0, fU = 0;
    #pragma unroll
    for (int j = 0; j < 8; ++j) {
        u64 v = partial[s * BPS + j0 + j];
        fI += (int)(unsigned)(v & 0xffffffffu);
        fU += (int)(unsigned)(v >> 32);
    }
    #pragma unroll
    for (int m = 1; m < 8; m <<= 1) {          // 8-lane group reduce (within wave)
        fI += __shfl_xor(fI, m);
        fU += __shfl_xor(fU, m);
    }
    __shared__ float sIou[SLICES];
    if ((t & 7) == 0) sIou[s] = (float)fI / ((float)fU + 1e-7f);
    __syncthreads();
    if (t < 64) {
        float x = (t < SLICES) ? sIou[t] : 0.0f;
        for (int off = 32; off; off >>= 1) x += __shfl_down(x, off);
        if (t == 0) out[0] = x * (100.0f / (float)SLICES);
    }
}

extern "C" void kernel_launch(void* const* d_in, const int* in_sizes, int n_in,
                              void* d_out, int out_size, void* d_ws, size_t ws_size,
                              hipStream_t stream) {
    const float4* A = (const float4*)d_in[0];
    const float4* B = (const float4*)d_in[1];
    u64* partial = (u64*)d_ws;
    float* out = (float*)d_out;

    jaccard_count<<<GRID, THREADS, 0, stream>>>(A, B, partial);
    jaccard_final<<<1, THREADS, 0, stream>>>(partial, out);
}